// Round 4
// baseline (433.387 us; speedup 1.0000x reference)
//
#include <hip/hip_runtime.h>
#include <math.h>

#define HDIM 256
#define WDIM 512
#define BB 32
#define HW (HDIM*WDIM)
#define NBIN 64   // accumulator replicas per variable (atomic de-contention)
#define SW 16     // splat strip width (64B-aligned sectors)

constexpr float PI_F = 3.14159265358979323846f;
constexpr float DEPTH_THRESH = 10.0f;
constexpr float BASELINE = 0.26f;
constexpr float ALPHA = 0.85f;
constexpr float LAMBDA_NORM = 0.05f;
constexpr float MMAP_COS_THRESH = 0.9f;
constexpr float EPS = 1e-6f;

__device__ __forceinline__ float attn_of_h(int h) {
  float theta = ((h + 0.5f) * (1.0f / HDIM) - 0.5f) * PI_F;
  float a = 1.0f - fabsf(theta) / (0.5f * PI_F);
  return fminf(fmaxf(a, 0.0f), 1.0f);
}

// acc layout: acc[var * NBIN + bin], vars 0..4
template <int N>
__device__ __forceinline__ void block_reduce_add(float (&v)[N], double* acc, int base) {
  #pragma unroll
  for (int off = 32; off; off >>= 1) {
    #pragma unroll
    for (int j = 0; j < N; j++) v[j] += __shfl_down(v[j], off);
  }
  __shared__ float sb[N * 4];
  int wid = threadIdx.x >> 6, lane = threadIdx.x & 63;
  if (lane == 0) {
    #pragma unroll
    for (int j = 0; j < N; j++) sb[j * 4 + wid] = v[j];
  }
  __syncthreads();
  if (threadIdx.x == 0) {
    int bin = blockIdx.x & (NBIN - 1);
    #pragma unroll
    for (int j = 0; j < N; j++) {
      float s = sb[j * 4 + 0] + sb[j * 4 + 1] + sb[j * 4 + 2] + sb[j * 4 + 3];
      atomicAdd(&acc[(base + j) * NBIN + bin], (double)s);
    }
  }
}

// ---------------- Splat: vertical 2-tap forward warp ----------
// 16-wide strips, float4 loads (4 px/thread), register prefetch, LDS accumulation.
// Vertical shift identity (exact): theta2 - theta = -atan(B*cos(th) / (d - B*sin(th)))
// (denominator >= d - B > 0, so principal branch is correct; cos(th) > 0.)
__global__ __launch_bounds__(256) void splat_kernel(
    const float* __restrict__ rgb, const float* __restrict__ depth,
    float* __restrict__ outw) {
  __shared__ float aw[HDIM * SW], ar[HDIM * SW], ag[HDIM * SW], ab[HDIM * SW];
  __shared__ float sTT[HDIM], cTT[HDIM];
  int blk = blockIdx.x;
  int b = blk >> 5;            // 32 strips of 16 cols per image
  int w0 = (blk & 31) << 4;
  int t = threadIdx.x;
  if (t < HDIM) {
    float th = ((t + 0.5f) * (1.0f / HDIM) - 0.5f) * PI_F;
    sTT[t] = sinf(th); cTT[t] = cosf(th);
  }
  for (int i = t; i < HDIM * SW; i += 256) { aw[i] = 0.f; ar[i] = 0.f; ag[i] = 0.f; ab[i] = 0.f; }
  __syncthreads();

  const float* dep = depth + (size_t)b * HW;
  const float* rg  = rgb + (size_t)b * 3 * HW;
  int wq = t & 3;              // which float4 within the 16-col strip
  int r0 = t >> 2;             // row within 64-row group (0..63)
  const float scale = (float)HDIM / PI_F;

  float4 dC, rC, gC, bC;
  {
    int g = r0 * WDIM + w0 + (wq << 2);
    dC = *(const float4*)(dep + g);
    rC = *(const float4*)(rg + g);
    gC = *(const float4*)(rg + HW + g);
    bC = *(const float4*)(rg + 2 * HW + g);
  }
  #pragma unroll
  for (int it = 0; it < 4; ++it) {
    int h = (it << 6) + r0;
    float4 d4 = dC, r4 = rC, g4 = gC, b4 = bC;
    if (it < 3) {
      int g = (h + 64) * WDIM + w0 + (wq << 2);
      dC = *(const float4*)(dep + g);
      rC = *(const float4*)(rg + g);
      gC = *(const float4*)(rg + HW + g);
      bC = *(const float4*)(rg + 2 * HW + g);
    }
    float st = sTT[h], ct = cTT[h];
    float bct = BASELINE * ct, bst = BASELINE * st;
    float dd[4] = {d4.x, d4.y, d4.z, d4.w};
    float rr[4] = {r4.x, r4.y, r4.z, r4.w};
    float gg2[4] = {g4.x, g4.y, g4.z, g4.w};
    float bb2[4] = {b4.x, b4.y, b4.z, b4.w};
    #pragma unroll
    for (int j = 0; j < 4; j++) {
      float d = dd[j];
      float delta = -atanf(bct / (d - bst));
      float cv = (float)h + delta * scale;
      float v0f = floorf(cv);
      int v0 = (int)v0f;
      float dv = cv - v0f;
      if (d < DEPTH_THRESH) {
        int wl = (wq << 2) + j;
        float r = rr[j], gch = gg2[j], bch = bb2[j];
        if (v0 >= 0 && v0 < HDIM) {
          float wgt = 1.f - dv; int a = v0 * SW + wl;
          atomicAdd(&aw[a], wgt); atomicAdd(&ar[a], r * wgt);
          atomicAdd(&ag[a], gch * wgt); atomicAdd(&ab[a], bch * wgt);
        }
        int v1 = v0 + 1;
        if (v1 >= 0 && v1 < HDIM) {
          float wgt = dv; int a = v1 * SW + wl;
          atomicAdd(&aw[a], wgt); atomicAdd(&ar[a], r * wgt);
          atomicAdd(&ag[a], gch * wgt); atomicAdd(&ab[a], bch * wgt);
        }
      }
    }
  }
  __syncthreads();
  // write out (float4, coalesced)
  for (int i = t; i < HDIM * (SW / 4); i += 256) {
    int h = i >> 2, q = i & 3;
    int a = h * SW + (q << 2);
    float4 w4 = *(float4*)&aw[a];
    float4 r4 = *(float4*)&ar[a];
    float4 g4 = *(float4*)&ag[a];
    float4 b4 = *(float4*)&ab[a];
    float ix = 1.f / fmaxf(w4.x, EPS), iy = 1.f / fmaxf(w4.y, EPS);
    float iz = 1.f / fmaxf(w4.z, EPS), iw = 1.f / fmaxf(w4.w, EPS);
    float4 ro = {r4.x * ix, r4.y * iy, r4.z * iz, r4.w * iw};
    float4 go = {g4.x * ix, g4.y * iy, g4.z * iz, g4.w * iw};
    float4 bo = {b4.x * ix, b4.y * iy, b4.z * iz, b4.w * iw};
    size_t g = (size_t)b * 3 * HW + h * WDIM + w0 + (q << 2);
    *(float4*)(outw + g) = ro;
    *(float4*)(outw + g + HW) = go;
    *(float4*)(outw + g + 2 * HW) = bo;
  }
}

// ---------------- Photo loss: separable 7x7 Gaussian SSIM + L1, tiled ----------
__global__ __launch_bounds__(256) void photo_kernel(
    const float* __restrict__ xw, const float* __restrict__ yr,
    const float* __restrict__ up_depth, double* __restrict__ acc) {
  __shared__ float xs[38 * 40];
  __shared__ float ys[38 * 40];
  __shared__ float rxs[1216], rys[1216], rxxs[1216], ryys[1216], rxys[1216];

  int bt = blockIdx.x;
  int b = bt >> 7;             // 128 tiles (8x16) per image
  int rem = bt & 127;
  int h0 = (rem >> 4) << 5;
  int w0 = (rem & 15) << 5;
  int t = threadIdx.x;

  float G[7];
  {
    float s = 0.f;
    #pragma unroll
    for (int i = 0; i < 7; i++) { float a = (float)(i - 3); G[i] = expf(-a * a / 4.5f); s += G[i]; }
    #pragma unroll
    for (int i = 0; i < 7; i++) G[i] /= s;
  }

  float dssim_a[4] = {0.f, 0.f, 0.f, 0.f};
  float l1_a[4] = {0.f, 0.f, 0.f, 0.f};
  const float C1 = 1e-4f, C2 = 9e-4f;

  for (int c = 0; c < 3; ++c) {
    const float* xp = xw + ((size_t)(b * 3 + c)) * HW;
    const float* yp = yr + ((size_t)(b * 3 + c)) * HW;
    __syncthreads();
    for (int i = t; i < 38 * 38; i += 256) {
      int r = i / 38, cc = i % 38;
      int gh = h0 - 3 + r, gw = w0 - 3 + cc;
      bool in = (gh >= 0) && (gh < HDIM) && (gw >= 0) && (gw < WDIM);
      float xv = in ? xp[gh * WDIM + gw] : 0.f;
      float yv = in ? yp[gh * WDIM + gw] : 0.f;
      xs[r * 40 + cc] = xv; ys[r * 40 + cc] = yv;
    }
    __syncthreads();
    for (int i = t; i < 1216; i += 256) {
      int r = i >> 5, cc = i & 31;
      const float* xrow = xs + r * 40 + cc;
      const float* yrow = ys + r * 40 + cc;
      float sx = 0.f, sy = 0.f, sxx = 0.f, syy = 0.f, sxy = 0.f;
      #pragma unroll
      for (int k = 0; k < 7; k++) {
        float gk = G[k]; float xv = xrow[k], yv = yrow[k];
        sx += gk * xv; sy += gk * yv;
        sxx += gk * xv * xv; syy += gk * yv * yv; sxy += gk * xv * yv;
      }
      rxs[i] = sx; rys[i] = sy; rxxs[i] = sxx; ryys[i] = syy; rxys[i] = sxy;
    }
    __syncthreads();
    #pragma unroll
    for (int q = 0; q < 4; q++) {
      int o = t + (q << 8);
      int oh = o >> 5, ow = o & 31;
      float mx = 0.f, my = 0.f, cxx = 0.f, cyy = 0.f, cxy = 0.f;
      #pragma unroll
      for (int k = 0; k < 7; k++) {
        float gk = G[k]; int ro = (oh + k) * 32 + ow;
        mx += gk * rxs[ro]; my += gk * rys[ro];
        cxx += gk * rxxs[ro]; cyy += gk * ryys[ro]; cxy += gk * rxys[ro];
      }
      float sxx = cxx - mx * mx, syy = cyy - my * my, sxy = cxy - mx * my;
      float ssim = ((2.f * mx * my + C1) * (2.f * sxy + C2)) /
                   ((mx * mx + my * my + C1) * (sxx + syy + C2));
      dssim_a[q] += (1.f - ssim) * 0.5f;
      l1_a[q] += fabsf(xs[(oh + 3) * 40 + ow + 3] - ys[(oh + 3) * 40 + ow + 3]);
    }
  }

  float sums[2] = {0.f, 0.f};
  #pragma unroll
  for (int q = 0; q < 4; q++) {
    int o = t + (q << 8);
    int oh = o >> 5, ow = o & 31;
    int h = h0 + oh, w = w0 + ow;
    float pl = ALPHA * (dssim_a[q] * (1.f / 3.f)) + (1.f - ALPHA) * (l1_a[q] * (1.f / 3.f));
    float cut = (up_depth[(size_t)b * HW + h * WDIM + w] < DEPTH_THRESH) ? 1.f : 0.f;
    float wm = cut * attn_of_h(h);
    sums[0] += pl * wm; sums[1] += wm;
  }
  block_reduce_add<2>(sums, acc, 0);
}

// ---------------- Smooth + normal losses (grid-stride: 4 px/thread) ----------
__global__ __launch_bounds__(256) void smoothnorm_kernel(
    const float* __restrict__ rgb, const float* __restrict__ depth,
    const float* __restrict__ up_depth, const float* __restrict__ vps,
    double* __restrict__ acc) {
  __shared__ float sT[HDIM], cT[HDIM], sP[WDIM], cP[WDIM];
  int t = threadIdx.x;
  if (t < HDIM) {
    float th = ((t + 0.5f) * (1.0f / HDIM) - 0.5f) * PI_F;
    sT[t] = sinf(th); cT[t] = cosf(th);
  }
  for (int i = t; i < WDIM; i += 256) {
    float ph = ((i + 0.5f) * (1.0f / WDIM) - 0.5f) * 2.0f * PI_F;
    sP[i] = sinf(ph); cP[i] = cosf(ph);
  }
  __syncthreads();

  int b = blockIdx.x >> 7;                     // 128 blocks per image
  int seg = (blockIdx.x & 127) << 10;          // 1024 px per block
  const float* dep = depth + (size_t)b * HW;
  const float* rg  = rgb + (size_t)b * 3 * HW;

  const float* vp = vps + b * 9;
  float vnx[3], vny[3], vnz[3], an[3];
  #pragma unroll
  for (int k = 0; k < 3; k++) {
    float vx = vp[3 * k], vy = vp[3 * k + 1], vz = vp[3 * k + 2];
    float vn = sqrtf(vx * vx + vy * vy + vz * vz);
    float iv = 1.f / (vn + EPS);
    vnx[k] = vx * iv; vny[k] = vy * iv; vnz[k] = vz * iv;
    an[k] = sqrtf(vnx[k] * vnx[k] + vny[k] * vny[k] + vnz[k] * vnz[k]);
  }

  float sums[3] = {0.f, 0.f, 0.f};

  #pragma unroll
  for (int p = 0; p < 4; ++p) {
    int hw = seg + (p << 8) + t;
    int h = hw >> 9, w = hw & (WDIM - 1);
    float d00 = dep[hw];

    float su = 0.f, gu = 0.f;
    if (w < WDIM - 1) {
      float d01 = dep[hw + 1];
      float ax = d01 * cT[h] * cP[w + 1] - d00 * cT[h] * cP[w];
      float ay = (d01 - d00) * sT[h];
      float az = d01 * cT[h] * sP[w + 1] - d00 * cT[h] * sP[w];
      su = fabsf(ax) + fabsf(ay) + fabsf(az);
      gu = fabsf(rg[hw + 1] - rg[hw]) + fabsf(rg[HW + hw + 1] - rg[HW + hw]) +
           fabsf(rg[2 * HW + hw + 1] - rg[2 * HW + hw]);
    }
    float sv = 0.f, gv = 0.f;
    if (h < HDIM - 1) {
      float d10 = dep[hw + WDIM];
      float ax = d10 * cT[h + 1] * cP[w] - d00 * cT[h] * cP[w];
      float ay = d10 * sT[h + 1] - d00 * sT[h];
      float az = d10 * cT[h + 1] * sP[w] - d00 * cT[h] * sP[w];
      sv = fabsf(ax) + fabsf(ay) + fabsf(az);
      gv = fabsf(rg[hw + WDIM] - rg[hw]) + fabsf(rg[HW + hw + WDIM] - rg[HW + hw]) +
           fabsf(rg[2 * HW + hw + WDIM] - rg[2 * HW + hw]);
    }
    float cut = (up_depth[(size_t)b * HW + hw] < DEPTH_THRESH) ? 1.f : 0.f;
    float wsm = (1.f - attn_of_h(h)) * cut;
    float smooth_c = (su * expf(-gu) + sv * expf(-gv)) * wsm;

    // normals (roll +/-3 with wrap on both axes)
    int wp = (w + 3) & (WDIM - 1), wmi = (w - 3) & (WDIM - 1);
    int hp = (h + 3) & (HDIM - 1), hm = (h - 3) & (HDIM - 1);
    float dwp = dep[h * WDIM + wp], dwm = dep[h * WDIM + wmi];
    float dhp = dep[hp * WDIM + w], dhm = dep[hm * WDIM + w];

    float pux = dwp * cT[h] * cP[wp] - dwm * cT[h] * cP[wmi];
    float puy = (dwp - dwm) * sT[h];
    float puz = dwp * cT[h] * sP[wp] - dwm * cT[h] * sP[wmi];
    float pvx = dhp * cT[hp] * cP[w] - dhm * cT[hm] * cP[w];
    float pvy = dhp * sT[hp] - dhm * sT[hm];
    float pvz = dhp * cT[hp] * sP[w] - dhm * cT[hm] * sP[w];
    // n = cross(dpv, dpu)
    float nx = pvy * puz - pvz * puy;
    float ny = pvz * pux - pvx * puz;
    float nz = pvx * puy - pvy * pux;
    float nn = sqrtf(nx * nx + ny * ny + nz * nz);
    float invn = 1.f / (nn + EPS);
    float px = nx * invn, py = ny * invn, pz = nz * invn;

    float s0 = vnx[0] * px + vny[0] * py + vnz[0] * pz;
    float s1 = vnx[1] * px + vny[1] * py + vnz[1] * pz;
    float s2 = vnx[2] * px + vny[2] * py + vnz[2] * pz;
    float best = s0; int kb = 0;
    if (s1 > best) { best = s1; kb = 1; }
    if (s2 > best) { best = s2; kb = 2; }
    if (-s0 > best) { best = -s0; kb = 0; }
    if (-s1 > best) { best = -s1; kb = 1; }
    if (-s2 > best) { best = -s2; kb = 2; }
    float pnn = sqrtf(px * px + py * py + pz * pz);
    float cossim = best / (pnn * an[kb] + EPS);
    if (isnan(cossim)) cossim = 1.0f;
    float contrib = (best > MMAP_COS_THRESH) ? (1.f - cossim) : 0.f;

    sums[0] += smooth_c; sums[1] += cut; sums[2] += contrib;
  }
  block_reduce_add<3>(sums, acc, 2);
}

__global__ void finalize_kernel(const double* __restrict__ acc, float* __restrict__ out) {
  if (threadIdx.x == 0 && blockIdx.x == 0) {
    double a[5];
    #pragma unroll
    for (int v = 0; v < 5; v++) {
      double s = 0.0;
      for (int i = 0; i < NBIN; i++) s += acc[v * NBIN + i];
      a[v] = s;
    }
    double photo = a[0] / (a[1] + (double)EPS);
    double smooth = a[2] / (a[3] + (double)EPS);
    double norml = a[4] / (double)((size_t)BB * HW);
    out[0] = (float)(photo + 0.1 * smooth + (double)LAMBDA_NORM * norml);
  }
}

extern "C" void kernel_launch(void* const* d_in, const int* in_sizes, int n_in,
                              void* d_out, int out_size, void* d_ws, size_t ws_size,
                              hipStream_t stream) {
  (void)in_sizes; (void)n_in; (void)out_size; (void)ws_size;
  const float* left_rgb = (const float*)d_in[0];
  const float* left_depth = (const float*)d_in[1];
  const float* up_depth = (const float*)d_in[2];
  const float* up_rgb = (const float*)d_in[3];
  const float* vps = (const float*)d_in[4];

  double* acc = (double*)d_ws;               // 5 vars x NBIN doubles = 2560 B
  float* warp = (float*)((char*)d_ws + 4096);

  hipMemsetAsync(d_ws, 0, 5 * NBIN * sizeof(double), stream);
  splat_kernel<<<BB * (WDIM / SW), 256, 0, stream>>>(left_rgb, left_depth, warp);
  photo_kernel<<<BB * (HDIM / 32) * (WDIM / 32), 256, 0, stream>>>(warp, up_rgb, up_depth, acc);
  smoothnorm_kernel<<<BB * 128, 256, 0, stream>>>(left_rgb, left_depth, up_depth, vps, acc);
  finalize_kernel<<<1, 64, 0, stream>>>(acc, (float*)d_out);
}

// Round 5
// 431.305 us; speedup vs baseline: 1.0048x; 1.0048x over previous
//
#include <hip/hip_runtime.h>
#include <math.h>

#define HDIM 256
#define WDIM 512
#define BB 32
#define HW (HDIM*WDIM)
#define NBIN 64   // accumulator replicas per variable (atomic de-contention)
#define SW 16     // splat strip width (64B-aligned sectors)

constexpr float PI_F = 3.14159265358979323846f;
constexpr float DEPTH_THRESH = 10.0f;
constexpr float BASELINE = 0.26f;
constexpr float ALPHA = 0.85f;
constexpr float LAMBDA_NORM = 0.05f;
constexpr float MMAP_COS_THRESH = 0.9f;
constexpr float EPS = 1e-6f;

__device__ __forceinline__ float attn_of_h(int h) {
  float theta = ((h + 0.5f) * (1.0f / HDIM) - 0.5f) * PI_F;
  float a = 1.0f - fabsf(theta) / (0.5f * PI_F);
  return fminf(fmaxf(a, 0.0f), 1.0f);
}

// acc layout: acc[var * NBIN + bin], vars 0..4
template <int N>
__device__ __forceinline__ void block_reduce_add(float (&v)[N], double* acc, int base) {
  #pragma unroll
  for (int off = 32; off; off >>= 1) {
    #pragma unroll
    for (int j = 0; j < N; j++) v[j] += __shfl_down(v[j], off);
  }
  __shared__ float sb[N * 4];
  int wid = threadIdx.x >> 6, lane = threadIdx.x & 63;
  if (lane == 0) {
    #pragma unroll
    for (int j = 0; j < N; j++) sb[j * 4 + wid] = v[j];
  }
  __syncthreads();
  if (threadIdx.x == 0) {
    int bin = blockIdx.x & (NBIN - 1);
    #pragma unroll
    for (int j = 0; j < N; j++) {
      float s = sb[j * 4 + 0] + sb[j * 4 + 1] + sb[j * 4 + 2] + sb[j * 4 + 3];
      unsafeAtomicAdd(&acc[(base + j) * NBIN + bin], (double)s);  // native global_atomic_add_f64
    }
  }
}

// ---------------- Splat: vertical 2-tap forward warp ----------
// 16-wide strips, float4 loads (4 px/thread), register prefetch, LDS accumulation.
// Vertical shift identity (exact): theta2 - theta = -atan(B*cos(th) / (d - B*sin(th)))
// (denominator >= d - B > 0, so principal branch is correct; cos(th) > 0.)
// LDS accumulation via unsafeAtomicAdd -> native ds_add_f32 (plain atomicAdd
// compiles to a ds_cmpst CAS retry loop = ~240cy serial chain per tap).
__global__ __launch_bounds__(256) void splat_kernel(
    const float* __restrict__ rgb, const float* __restrict__ depth,
    float* __restrict__ outw) {
  __shared__ float aw[HDIM * SW], ar[HDIM * SW], ag[HDIM * SW], ab[HDIM * SW];
  __shared__ float sTT[HDIM], cTT[HDIM];
  int blk = blockIdx.x;
  int b = blk >> 5;            // 32 strips of 16 cols per image
  int w0 = (blk & 31) << 4;
  int t = threadIdx.x;
  if (t < HDIM) {
    float th = ((t + 0.5f) * (1.0f / HDIM) - 0.5f) * PI_F;
    sTT[t] = sinf(th); cTT[t] = cosf(th);
  }
  for (int i = t; i < HDIM * SW; i += 256) { aw[i] = 0.f; ar[i] = 0.f; ag[i] = 0.f; ab[i] = 0.f; }
  __syncthreads();

  const float* dep = depth + (size_t)b * HW;
  const float* rg  = rgb + (size_t)b * 3 * HW;
  int wq = t & 3;              // which float4 within the 16-col strip
  int r0 = t >> 2;             // row within 64-row group (0..63)
  const float scale = (float)HDIM / PI_F;

  float4 dC, rC, gC, bC;
  {
    int g = r0 * WDIM + w0 + (wq << 2);
    dC = *(const float4*)(dep + g);
    rC = *(const float4*)(rg + g);
    gC = *(const float4*)(rg + HW + g);
    bC = *(const float4*)(rg + 2 * HW + g);
  }
  #pragma unroll
  for (int it = 0; it < 4; ++it) {
    int h = (it << 6) + r0;
    float4 d4 = dC, r4 = rC, g4 = gC, b4 = bC;
    if (it < 3) {
      int g = (h + 64) * WDIM + w0 + (wq << 2);
      dC = *(const float4*)(dep + g);
      rC = *(const float4*)(rg + g);
      gC = *(const float4*)(rg + HW + g);
      bC = *(const float4*)(rg + 2 * HW + g);
    }
    float st = sTT[h], ct = cTT[h];
    float bct = BASELINE * ct, bst = BASELINE * st;
    float dd[4] = {d4.x, d4.y, d4.z, d4.w};
    float rr[4] = {r4.x, r4.y, r4.z, r4.w};
    float gg2[4] = {g4.x, g4.y, g4.z, g4.w};
    float bb2[4] = {b4.x, b4.y, b4.z, b4.w};
    #pragma unroll
    for (int j = 0; j < 4; j++) {
      float d = dd[j];
      float delta = -atanf(bct / (d - bst));
      float cv = (float)h + delta * scale;
      float v0f = floorf(cv);
      int v0 = (int)v0f;
      float dv = cv - v0f;
      if (d < DEPTH_THRESH) {
        int wl = (wq << 2) + j;
        float r = rr[j], gch = gg2[j], bch = bb2[j];
        if (v0 >= 0 && v0 < HDIM) {
          float wgt = 1.f - dv; int a = v0 * SW + wl;
          unsafeAtomicAdd(&aw[a], wgt); unsafeAtomicAdd(&ar[a], r * wgt);
          unsafeAtomicAdd(&ag[a], gch * wgt); unsafeAtomicAdd(&ab[a], bch * wgt);
        }
        int v1 = v0 + 1;
        if (v1 >= 0 && v1 < HDIM) {
          float wgt = dv; int a = v1 * SW + wl;
          unsafeAtomicAdd(&aw[a], wgt); unsafeAtomicAdd(&ar[a], r * wgt);
          unsafeAtomicAdd(&ag[a], gch * wgt); unsafeAtomicAdd(&ab[a], bch * wgt);
        }
      }
    }
  }
  __syncthreads();
  // write out (float4, coalesced)
  for (int i = t; i < HDIM * (SW / 4); i += 256) {
    int h = i >> 2, q = i & 3;
    int a = h * SW + (q << 2);
    float4 w4 = *(float4*)&aw[a];
    float4 r4 = *(float4*)&ar[a];
    float4 g4 = *(float4*)&ag[a];
    float4 b4 = *(float4*)&ab[a];
    float ix = 1.f / fmaxf(w4.x, EPS), iy = 1.f / fmaxf(w4.y, EPS);
    float iz = 1.f / fmaxf(w4.z, EPS), iw = 1.f / fmaxf(w4.w, EPS);
    float4 ro = {r4.x * ix, r4.y * iy, r4.z * iz, r4.w * iw};
    float4 go = {g4.x * ix, g4.y * iy, g4.z * iz, g4.w * iw};
    float4 bo = {b4.x * ix, b4.y * iy, b4.z * iz, b4.w * iw};
    size_t g = (size_t)b * 3 * HW + h * WDIM + w0 + (q << 2);
    *(float4*)(outw + g) = ro;
    *(float4*)(outw + g + HW) = go;
    *(float4*)(outw + g + 2 * HW) = bo;
  }
}

// ---------------- Photo loss: separable 7x7 Gaussian SSIM + L1, tiled ----------
__global__ __launch_bounds__(256) void photo_kernel(
    const float* __restrict__ xw, const float* __restrict__ yr,
    const float* __restrict__ up_depth, double* __restrict__ acc) {
  __shared__ float xs[38 * 40];
  __shared__ float ys[38 * 40];
  __shared__ float rxs[1216], rys[1216], rxxs[1216], ryys[1216], rxys[1216];

  int bt = blockIdx.x;
  int b = bt >> 7;             // 128 tiles (8x16) per image
  int rem = bt & 127;
  int h0 = (rem >> 4) << 5;
  int w0 = (rem & 15) << 5;
  int t = threadIdx.x;

  float G[7];
  {
    float s = 0.f;
    #pragma unroll
    for (int i = 0; i < 7; i++) { float a = (float)(i - 3); G[i] = expf(-a * a / 4.5f); s += G[i]; }
    #pragma unroll
    for (int i = 0; i < 7; i++) G[i] /= s;
  }

  float dssim_a[4] = {0.f, 0.f, 0.f, 0.f};
  float l1_a[4] = {0.f, 0.f, 0.f, 0.f};
  const float C1 = 1e-4f, C2 = 9e-4f;

  for (int c = 0; c < 3; ++c) {
    const float* xp = xw + ((size_t)(b * 3 + c)) * HW;
    const float* yp = yr + ((size_t)(b * 3 + c)) * HW;
    __syncthreads();
    for (int i = t; i < 38 * 38; i += 256) {
      int r = i / 38, cc = i % 38;
      int gh = h0 - 3 + r, gw = w0 - 3 + cc;
      bool in = (gh >= 0) && (gh < HDIM) && (gw >= 0) && (gw < WDIM);
      float xv = in ? xp[gh * WDIM + gw] : 0.f;
      float yv = in ? yp[gh * WDIM + gw] : 0.f;
      xs[r * 40 + cc] = xv; ys[r * 40 + cc] = yv;
    }
    __syncthreads();
    for (int i = t; i < 1216; i += 256) {
      int r = i >> 5, cc = i & 31;
      const float* xrow = xs + r * 40 + cc;
      const float* yrow = ys + r * 40 + cc;
      float sx = 0.f, sy = 0.f, sxx = 0.f, syy = 0.f, sxy = 0.f;
      #pragma unroll
      for (int k = 0; k < 7; k++) {
        float gk = G[k]; float xv = xrow[k], yv = yrow[k];
        sx += gk * xv; sy += gk * yv;
        sxx += gk * xv * xv; syy += gk * yv * yv; sxy += gk * xv * yv;
      }
      rxs[i] = sx; rys[i] = sy; rxxs[i] = sxx; ryys[i] = syy; rxys[i] = sxy;
    }
    __syncthreads();
    #pragma unroll
    for (int q = 0; q < 4; q++) {
      int o = t + (q << 8);
      int oh = o >> 5, ow = o & 31;
      float mx = 0.f, my = 0.f, cxx = 0.f, cyy = 0.f, cxy = 0.f;
      #pragma unroll
      for (int k = 0; k < 7; k++) {
        float gk = G[k]; int ro = (oh + k) * 32 + ow;
        mx += gk * rxs[ro]; my += gk * rys[ro];
        cxx += gk * rxxs[ro]; cyy += gk * ryys[ro]; cxy += gk * rxys[ro];
      }
      float sxx = cxx - mx * mx, syy = cyy - my * my, sxy = cxy - mx * my;
      float ssim = ((2.f * mx * my + C1) * (2.f * sxy + C2)) /
                   ((mx * mx + my * my + C1) * (sxx + syy + C2));
      dssim_a[q] += (1.f - ssim) * 0.5f;
      l1_a[q] += fabsf(xs[(oh + 3) * 40 + ow + 3] - ys[(oh + 3) * 40 + ow + 3]);
    }
  }

  float sums[2] = {0.f, 0.f};
  #pragma unroll
  for (int q = 0; q < 4; q++) {
    int o = t + (q << 8);
    int oh = o >> 5, ow = o & 31;
    int h = h0 + oh, w = w0 + ow;
    float pl = ALPHA * (dssim_a[q] * (1.f / 3.f)) + (1.f - ALPHA) * (l1_a[q] * (1.f / 3.f));
    float cut = (up_depth[(size_t)b * HW + h * WDIM + w] < DEPTH_THRESH) ? 1.f : 0.f;
    float wm = cut * attn_of_h(h);
    sums[0] += pl * wm; sums[1] += wm;
  }
  block_reduce_add<2>(sums, acc, 0);
}

// ---------------- Smooth + normal losses (grid-stride: 4 px/thread) ----------
__global__ __launch_bounds__(256) void smoothnorm_kernel(
    const float* __restrict__ rgb, const float* __restrict__ depth,
    const float* __restrict__ up_depth, const float* __restrict__ vps,
    double* __restrict__ acc) {
  __shared__ float sT[HDIM], cT[HDIM], sP[WDIM], cP[WDIM];
  int t = threadIdx.x;
  if (t < HDIM) {
    float th = ((t + 0.5f) * (1.0f / HDIM) - 0.5f) * PI_F;
    sT[t] = sinf(th); cT[t] = cosf(th);
  }
  for (int i = t; i < WDIM; i += 256) {
    float ph = ((i + 0.5f) * (1.0f / WDIM) - 0.5f) * 2.0f * PI_F;
    sP[i] = sinf(ph); cP[i] = cosf(ph);
  }
  __syncthreads();

  int b = blockIdx.x >> 7;                     // 128 blocks per image
  int seg = (blockIdx.x & 127) << 10;          // 1024 px per block
  const float* dep = depth + (size_t)b * HW;
  const float* rg  = rgb + (size_t)b * 3 * HW;

  const float* vp = vps + b * 9;
  float vnx[3], vny[3], vnz[3], an[3];
  #pragma unroll
  for (int k = 0; k < 3; k++) {
    float vx = vp[3 * k], vy = vp[3 * k + 1], vz = vp[3 * k + 2];
    float vn = sqrtf(vx * vx + vy * vy + vz * vz);
    float iv = 1.f / (vn + EPS);
    vnx[k] = vx * iv; vny[k] = vy * iv; vnz[k] = vz * iv;
    an[k] = sqrtf(vnx[k] * vnx[k] + vny[k] * vny[k] + vnz[k] * vnz[k]);
  }

  float sums[3] = {0.f, 0.f, 0.f};

  #pragma unroll
  for (int p = 0; p < 4; ++p) {
    int hw = seg + (p << 8) + t;
    int h = hw >> 9, w = hw & (WDIM - 1);
    float d00 = dep[hw];

    float su = 0.f, gu = 0.f;
    if (w < WDIM - 1) {
      float d01 = dep[hw + 1];
      float ax = d01 * cT[h] * cP[w + 1] - d00 * cT[h] * cP[w];
      float ay = (d01 - d00) * sT[h];
      float az = d01 * cT[h] * sP[w + 1] - d00 * cT[h] * sP[w];
      su = fabsf(ax) + fabsf(ay) + fabsf(az);
      gu = fabsf(rg[hw + 1] - rg[hw]) + fabsf(rg[HW + hw + 1] - rg[HW + hw]) +
           fabsf(rg[2 * HW + hw + 1] - rg[2 * HW + hw]);
    }
    float sv = 0.f, gv = 0.f;
    if (h < HDIM - 1) {
      float d10 = dep[hw + WDIM];
      float ax = d10 * cT[h + 1] * cP[w] - d00 * cT[h] * cP[w];
      float ay = d10 * sT[h + 1] - d00 * sT[h];
      float az = d10 * cT[h + 1] * sP[w] - d00 * cT[h] * sP[w];
      sv = fabsf(ax) + fabsf(ay) + fabsf(az);
      gv = fabsf(rg[hw + WDIM] - rg[hw]) + fabsf(rg[HW + hw + WDIM] - rg[HW + hw]) +
           fabsf(rg[2 * HW + hw + WDIM] - rg[2 * HW + hw]);
    }
    float cut = (up_depth[(size_t)b * HW + hw] < DEPTH_THRESH) ? 1.f : 0.f;
    float wsm = (1.f - attn_of_h(h)) * cut;
    float smooth_c = (su * expf(-gu) + sv * expf(-gv)) * wsm;

    // normals (roll +/-3 with wrap on both axes)
    int wp = (w + 3) & (WDIM - 1), wmi = (w - 3) & (WDIM - 1);
    int hp = (h + 3) & (HDIM - 1), hm = (h - 3) & (HDIM - 1);
    float dwp = dep[h * WDIM + wp], dwm = dep[h * WDIM + wmi];
    float dhp = dep[hp * WDIM + w], dhm = dep[hm * WDIM + w];

    float pux = dwp * cT[h] * cP[wp] - dwm * cT[h] * cP[wmi];
    float puy = (dwp - dwm) * sT[h];
    float puz = dwp * cT[h] * sP[wp] - dwm * cT[h] * sP[wmi];
    float pvx = dhp * cT[hp] * cP[w] - dhm * cT[hm] * cP[w];
    float pvy = dhp * sT[hp] - dhm * sT[hm];
    float pvz = dhp * cT[hp] * sP[w] - dhm * cT[hm] * sP[w];
    // n = cross(dpv, dpu)
    float nx = pvy * puz - pvz * puy;
    float ny = pvz * pux - pvx * puz;
    float nz = pvx * puy - pvy * pux;
    float nn = sqrtf(nx * nx + ny * ny + nz * nz);
    float invn = 1.f / (nn + EPS);
    float px = nx * invn, py = ny * invn, pz = nz * invn;

    float s0 = vnx[0] * px + vny[0] * py + vnz[0] * pz;
    float s1 = vnx[1] * px + vny[1] * py + vnz[1] * pz;
    float s2 = vnx[2] * px + vny[2] * py + vnz[2] * pz;
    float best = s0; int kb = 0;
    if (s1 > best) { best = s1; kb = 1; }
    if (s2 > best) { best = s2; kb = 2; }
    if (-s0 > best) { best = -s0; kb = 0; }
    if (-s1 > best) { best = -s1; kb = 1; }
    if (-s2 > best) { best = -s2; kb = 2; }
    float pnn = sqrtf(px * px + py * py + pz * pz);
    float cossim = best / (pnn * an[kb] + EPS);
    if (isnan(cossim)) cossim = 1.0f;
    float contrib = (best > MMAP_COS_THRESH) ? (1.f - cossim) : 0.f;

    sums[0] += smooth_c; sums[1] += cut; sums[2] += contrib;
  }
  block_reduce_add<3>(sums, acc, 2);
}

__global__ void finalize_kernel(const double* __restrict__ acc, float* __restrict__ out) {
  if (threadIdx.x == 0 && blockIdx.x == 0) {
    double a[5];
    #pragma unroll
    for (int v = 0; v < 5; v++) {
      double s = 0.0;
      for (int i = 0; i < NBIN; i++) s += acc[v * NBIN + i];
      a[v] = s;
    }
    double photo = a[0] / (a[1] + (double)EPS);
    double smooth = a[2] / (a[3] + (double)EPS);
    double norml = a[4] / (double)((size_t)BB * HW);
    out[0] = (float)(photo + 0.1 * smooth + (double)LAMBDA_NORM * norml);
  }
}

extern "C" void kernel_launch(void* const* d_in, const int* in_sizes, int n_in,
                              void* d_out, int out_size, void* d_ws, size_t ws_size,
                              hipStream_t stream) {
  (void)in_sizes; (void)n_in; (void)out_size; (void)ws_size;
  const float* left_rgb = (const float*)d_in[0];
  const float* left_depth = (const float*)d_in[1];
  const float* up_depth = (const float*)d_in[2];
  const float* up_rgb = (const float*)d_in[3];
  const float* vps = (const float*)d_in[4];

  double* acc = (double*)d_ws;               // 5 vars x NBIN doubles = 2560 B
  float* warp = (float*)((char*)d_ws + 4096);

  hipMemsetAsync(d_ws, 0, 5 * NBIN * sizeof(double), stream);
  splat_kernel<<<BB * (WDIM / SW), 256, 0, stream>>>(left_rgb, left_depth, warp);
  photo_kernel<<<BB * (HDIM / 32) * (WDIM / 32), 256, 0, stream>>>(warp, up_rgb, up_depth, acc);
  smoothnorm_kernel<<<BB * 128, 256, 0, stream>>>(left_rgb, left_depth, up_depth, vps, acc);
  finalize_kernel<<<1, 64, 0, stream>>>(acc, (float*)d_out);
}

// Round 6
// 380.848 us; speedup vs baseline: 1.1380x; 1.1325x over previous
//
#include <hip/hip_runtime.h>
#include <math.h>

#define HDIM 256
#define WDIM 512
#define BB 32
#define HW (HDIM*WDIM)
#define NBIN 64   // accumulator replicas per variable (atomic de-contention)
#define SW 16     // splat strip width (64B-aligned sectors)
#define SCAN 48   // gather window: max vertical shift 44.55px (analytic, d>=0.5) + tap +margin
#define STR 260   // transposed LDS stride (floats): 260*4B, b128-aligned, 2-way-conflict max

constexpr float PI_F = 3.14159265358979323846f;
constexpr float DEPTH_THRESH = 10.0f;
constexpr float BASELINE = 0.26f;
constexpr float ALPHA = 0.85f;
constexpr float LAMBDA_NORM = 0.05f;
constexpr float MMAP_COS_THRESH = 0.9f;
constexpr float EPS = 1e-6f;

__device__ __forceinline__ float attn_of_h(int h) {
  float theta = ((h + 0.5f) * (1.0f / HDIM) - 0.5f) * PI_F;
  float a = 1.0f - fabsf(theta) / (0.5f * PI_F);
  return fminf(fmaxf(a, 0.0f), 1.0f);
}

// acc layout: acc[var * NBIN + bin], vars 0..4
template <int N>
__device__ __forceinline__ void block_reduce_add(float (&v)[N], double* acc, int base) {
  #pragma unroll
  for (int off = 32; off; off >>= 1) {
    #pragma unroll
    for (int j = 0; j < N; j++) v[j] += __shfl_down(v[j], off);
  }
  __shared__ float sb[N * 4];
  int wid = threadIdx.x >> 6, lane = threadIdx.x & 63;
  if (lane == 0) {
    #pragma unroll
    for (int j = 0; j < N; j++) sb[j * 4 + wid] = v[j];
  }
  __syncthreads();
  if (threadIdx.x == 0) {
    int bin = blockIdx.x & (NBIN - 1);
    #pragma unroll
    for (int j = 0; j < N; j++) {
      float s = sb[j * 4 + 0] + sb[j * 4 + 1] + sb[j * 4 + 2] + sb[j * 4 + 3];
      unsafeAtomicAdd(&acc[(base + j) * NBIN + bin], (double)s);
    }
  }
}

// ---------------- Splat: vertical 2-tap forward warp, GATHER formulation ----------
// No atomics. Stage cv + rgb into transposed LDS, then each output row h gathers
// from sources s in [h, h+SCAN-1] (cv = s - shift, shift in (0, 44.6] px).
// Vertical shift identity (exact): theta2 - theta = -atan(B*cos(th)/(d - B*sin(th))).
__global__ __launch_bounds__(256) void splat_kernel(
    const float* __restrict__ rgb, const float* __restrict__ depth,
    float* __restrict__ outw) {
  __shared__ float cv_t[SW][STR];
  __shared__ float r_t[SW][STR], g_t[SW][STR], b_t[SW][STR];
  __shared__ float sTT[HDIM], cTT[HDIM];
  int blk = blockIdx.x;
  int b = blk >> 5;            // 32 strips of 16 cols per image
  int w0 = (blk & 31) << 4;
  int t = threadIdx.x;
  if (t < HDIM) {
    float th = ((t + 0.5f) * (1.0f / HDIM) - 0.5f) * PI_F;
    sTT[t] = sinf(th); cTT[t] = cosf(th);
  }
  __syncthreads();

  const float* dep = depth + (size_t)b * HW;
  const float* rg  = rgb + (size_t)b * 3 * HW;
  int wq = t & 3;              // which float4 within the 16-col strip
  int r0 = t >> 2;             // row within 64-row group (0..63)
  const float scale = (float)HDIM / PI_F;

  // ---- stage phase: compute cv per pixel, store cv+rgb transposed ----
  float4 dC, rC, gC, bC;
  {
    int g = r0 * WDIM + w0 + (wq << 2);
    dC = *(const float4*)(dep + g);
    rC = *(const float4*)(rg + g);
    gC = *(const float4*)(rg + HW + g);
    bC = *(const float4*)(rg + 2 * HW + g);
  }
  #pragma unroll
  for (int it = 0; it < 4; ++it) {
    int h = (it << 6) + r0;
    float4 d4 = dC, r4 = rC, g4 = gC, b4 = bC;
    if (it < 3) {
      int g = (h + 64) * WDIM + w0 + (wq << 2);
      dC = *(const float4*)(dep + g);
      rC = *(const float4*)(rg + g);
      gC = *(const float4*)(rg + HW + g);
      bC = *(const float4*)(rg + 2 * HW + g);
    }
    float st = sTT[h], ct = cTT[h];
    float bct = BASELINE * ct, bst = BASELINE * st;
    float dd[4] = {d4.x, d4.y, d4.z, d4.w};
    float rr[4] = {r4.x, r4.y, r4.z, r4.w};
    float gg2[4] = {g4.x, g4.y, g4.z, g4.w};
    float bb2[4] = {b4.x, b4.y, b4.z, b4.w};
    #pragma unroll
    for (int j = 0; j < 4; j++) {
      float d = dd[j];
      float delta = -atanf(bct / (d - bst));
      float cv = (float)h + delta * scale;
      if (!(d < DEPTH_THRESH)) cv = 1e9f;   // invalid sentinel: never matches
      int wl = (wq << 2) + j;
      cv_t[wl][h] = cv;
      r_t[wl][h] = rr[j];
      g_t[wl][h] = gg2[j];
      b_t[wl][h] = bb2[j];
    }
  }
  __syncthreads();

  // ---- gather phase: each thread owns 16 output rows of one column ----
  int wl = t & 15;
  int hbase = t >> 4;          // 0..15
  size_t obase = (size_t)b * 3 * HW + w0 + wl;
  const float* cvrow = &cv_t[wl][0];
  const float* rrow = &r_t[wl][0];
  const float* grow = &g_t[wl][0];
  const float* brow = &b_t[wl][0];
  for (int k = 0; k < 16; ++k) {
    int h = (k << 4) + hbase;
    float hf = (float)h;
    int smax = min(h + SCAN - 1, HDIM - 1);
    float accw = 0.f, ar = 0.f, ag = 0.f, ab = 0.f;
    int gend = smax >> 2;
    for (int g = h >> 2; g <= gend; ++g) {
      float4 c4 = *(const float4*)(cvrow + (g << 2));
      float cs[4] = {c4.x, c4.y, c4.z, c4.w};
      #pragma unroll
      for (int j = 0; j < 4; ++j) {
        float c = cs[j];
        float v0f = floorf(c);
        float dv = c - v0f;
        // tap1: floor(cv)==h gets (1-dv); tap2: floor(cv)==h-1 gets dv.
        float wgt = (v0f == hf) ? (1.f - dv) : ((v0f == hf - 1.f) ? dv : 0.f);
        if (wgt > 0.f) {
          int s = (g << 2) + j;
          accw += wgt;
          ar += wgt * rrow[s];
          ag += wgt * grow[s];
          ab += wgt * brow[s];
        }
      }
    }
    float inv = 1.f / fmaxf(accw, EPS);
    size_t o = obase + (size_t)h * WDIM;
    outw[o] = ar * inv;
    outw[o + HW] = ag * inv;
    outw[o + 2 * HW] = ab * inv;
  }
}

// ---------------- Photo loss: separable 7x7 Gaussian SSIM + L1, tiled ----------
__global__ __launch_bounds__(256) void photo_kernel(
    const float* __restrict__ xw, const float* __restrict__ yr,
    const float* __restrict__ up_depth, double* __restrict__ acc) {
  __shared__ float xs[38 * 40];
  __shared__ float ys[38 * 40];
  __shared__ float rxs[1216], rys[1216], rxxs[1216], ryys[1216], rxys[1216];

  int bt = blockIdx.x;
  int b = bt >> 7;             // 128 tiles (8x16) per image
  int rem = bt & 127;
  int h0 = (rem >> 4) << 5;
  int w0 = (rem & 15) << 5;
  int t = threadIdx.x;

  float G[7];
  {
    float s = 0.f;
    #pragma unroll
    for (int i = 0; i < 7; i++) { float a = (float)(i - 3); G[i] = expf(-a * a / 4.5f); s += G[i]; }
    #pragma unroll
    for (int i = 0; i < 7; i++) G[i] /= s;
  }

  float dssim_a[4] = {0.f, 0.f, 0.f, 0.f};
  float l1_a[4] = {0.f, 0.f, 0.f, 0.f};
  const float C1 = 1e-4f, C2 = 9e-4f;

  for (int c = 0; c < 3; ++c) {
    const float* xp = xw + ((size_t)(b * 3 + c)) * HW;
    const float* yp = yr + ((size_t)(b * 3 + c)) * HW;
    __syncthreads();
    for (int i = t; i < 38 * 38; i += 256) {
      int r = i / 38, cc = i % 38;
      int gh = h0 - 3 + r, gw = w0 - 3 + cc;
      bool in = (gh >= 0) && (gh < HDIM) && (gw >= 0) && (gw < WDIM);
      float xv = in ? xp[gh * WDIM + gw] : 0.f;
      float yv = in ? yp[gh * WDIM + gw] : 0.f;
      xs[r * 40 + cc] = xv; ys[r * 40 + cc] = yv;
    }
    __syncthreads();
    for (int i = t; i < 1216; i += 256) {
      int r = i >> 5, cc = i & 31;
      const float* xrow = xs + r * 40 + cc;
      const float* yrow = ys + r * 40 + cc;
      float sx = 0.f, sy = 0.f, sxx = 0.f, syy = 0.f, sxy = 0.f;
      #pragma unroll
      for (int k = 0; k < 7; k++) {
        float gk = G[k]; float xv = xrow[k], yv = yrow[k];
        sx += gk * xv; sy += gk * yv;
        sxx += gk * xv * xv; syy += gk * yv * yv; sxy += gk * xv * yv;
      }
      rxs[i] = sx; rys[i] = sy; rxxs[i] = sxx; ryys[i] = syy; rxys[i] = sxy;
    }
    __syncthreads();
    #pragma unroll
    for (int q = 0; q < 4; q++) {
      int o = t + (q << 8);
      int oh = o >> 5, ow = o & 31;
      float mx = 0.f, my = 0.f, cxx = 0.f, cyy = 0.f, cxy = 0.f;
      #pragma unroll
      for (int k = 0; k < 7; k++) {
        float gk = G[k]; int ro = (oh + k) * 32 + ow;
        mx += gk * rxs[ro]; my += gk * rys[ro];
        cxx += gk * rxxs[ro]; cyy += gk * ryys[ro]; cxy += gk * rxys[ro];
      }
      float sxx = cxx - mx * mx, syy = cyy - my * my, sxy = cxy - mx * my;
      float ssim = ((2.f * mx * my + C1) * (2.f * sxy + C2)) /
                   ((mx * mx + my * my + C1) * (sxx + syy + C2));
      dssim_a[q] += (1.f - ssim) * 0.5f;
      l1_a[q] += fabsf(xs[(oh + 3) * 40 + ow + 3] - ys[(oh + 3) * 40 + ow + 3]);
    }
  }

  float sums[2] = {0.f, 0.f};
  #pragma unroll
  for (int q = 0; q < 4; q++) {
    int o = t + (q << 8);
    int oh = o >> 5, ow = o & 31;
    int h = h0 + oh, w = w0 + ow;
    float pl = ALPHA * (dssim_a[q] * (1.f / 3.f)) + (1.f - ALPHA) * (l1_a[q] * (1.f / 3.f));
    float cut = (up_depth[(size_t)b * HW + h * WDIM + w] < DEPTH_THRESH) ? 1.f : 0.f;
    float wm = cut * attn_of_h(h);
    sums[0] += pl * wm; sums[1] += wm;
  }
  block_reduce_add<2>(sums, acc, 0);
}

// ---------------- Smooth + normal losses (grid-stride: 4 px/thread) ----------
__global__ __launch_bounds__(256) void smoothnorm_kernel(
    const float* __restrict__ rgb, const float* __restrict__ depth,
    const float* __restrict__ up_depth, const float* __restrict__ vps,
    double* __restrict__ acc) {
  __shared__ float sT[HDIM], cT[HDIM], sP[WDIM], cP[WDIM];
  int t = threadIdx.x;
  if (t < HDIM) {
    float th = ((t + 0.5f) * (1.0f / HDIM) - 0.5f) * PI_F;
    sT[t] = sinf(th); cT[t] = cosf(th);
  }
  for (int i = t; i < WDIM; i += 256) {
    float ph = ((i + 0.5f) * (1.0f / WDIM) - 0.5f) * 2.0f * PI_F;
    sP[i] = sinf(ph); cP[i] = cosf(ph);
  }
  __syncthreads();

  int b = blockIdx.x >> 7;                     // 128 blocks per image
  int seg = (blockIdx.x & 127) << 10;          // 1024 px per block
  const float* dep = depth + (size_t)b * HW;
  const float* rg  = rgb + (size_t)b * 3 * HW;

  const float* vp = vps + b * 9;
  float vnx[3], vny[3], vnz[3], an[3];
  #pragma unroll
  for (int k = 0; k < 3; k++) {
    float vx = vp[3 * k], vy = vp[3 * k + 1], vz = vp[3 * k + 2];
    float vn = sqrtf(vx * vx + vy * vy + vz * vz);
    float iv = 1.f / (vn + EPS);
    vnx[k] = vx * iv; vny[k] = vy * iv; vnz[k] = vz * iv;
    an[k] = sqrtf(vnx[k] * vnx[k] + vny[k] * vny[k] + vnz[k] * vnz[k]);
  }

  float sums[3] = {0.f, 0.f, 0.f};

  #pragma unroll
  for (int p = 0; p < 4; ++p) {
    int hw = seg + (p << 8) + t;
    int h = hw >> 9, w = hw & (WDIM - 1);
    float d00 = dep[hw];

    float su = 0.f, gu = 0.f;
    if (w < WDIM - 1) {
      float d01 = dep[hw + 1];
      float ax = d01 * cT[h] * cP[w + 1] - d00 * cT[h] * cP[w];
      float ay = (d01 - d00) * sT[h];
      float az = d01 * cT[h] * sP[w + 1] - d00 * cT[h] * sP[w];
      su = fabsf(ax) + fabsf(ay) + fabsf(az);
      gu = fabsf(rg[hw + 1] - rg[hw]) + fabsf(rg[HW + hw + 1] - rg[HW + hw]) +
           fabsf(rg[2 * HW + hw + 1] - rg[2 * HW + hw]);
    }
    float sv = 0.f, gv = 0.f;
    if (h < HDIM - 1) {
      float d10 = dep[hw + WDIM];
      float ax = d10 * cT[h + 1] * cP[w] - d00 * cT[h] * cP[w];
      float ay = d10 * sT[h + 1] - d00 * sT[h];
      float az = d10 * cT[h + 1] * sP[w] - d00 * cT[h] * sP[w];
      sv = fabsf(ax) + fabsf(ay) + fabsf(az);
      gv = fabsf(rg[hw + WDIM] - rg[hw]) + fabsf(rg[HW + hw + WDIM] - rg[HW + hw]) +
           fabsf(rg[2 * HW + hw + WDIM] - rg[2 * HW + hw]);
    }
    float cut = (up_depth[(size_t)b * HW + hw] < DEPTH_THRESH) ? 1.f : 0.f;
    float wsm = (1.f - attn_of_h(h)) * cut;
    float smooth_c = (su * expf(-gu) + sv * expf(-gv)) * wsm;

    // normals (roll +/-3 with wrap on both axes)
    int wp = (w + 3) & (WDIM - 1), wmi = (w - 3) & (WDIM - 1);
    int hp = (h + 3) & (HDIM - 1), hm = (h - 3) & (HDIM - 1);
    float dwp = dep[h * WDIM + wp], dwm = dep[h * WDIM + wmi];
    float dhp = dep[hp * WDIM + w], dhm = dep[hm * WDIM + w];

    float pux = dwp * cT[h] * cP[wp] - dwm * cT[h] * cP[wmi];
    float puy = (dwp - dwm) * sT[h];
    float puz = dwp * cT[h] * sP[wp] - dwm * cT[h] * sP[wmi];
    float pvx = dhp * cT[hp] * cP[w] - dhm * cT[hm] * cP[w];
    float pvy = dhp * sT[hp] - dhm * sT[hm];
    float pvz = dhp * cT[hp] * sP[w] - dhm * cT[hm] * sP[w];
    // n = cross(dpv, dpu)
    float nx = pvy * puz - pvz * puy;
    float ny = pvz * pux - pvx * puz;
    float nz = pvx * puy - pvy * pux;
    float nn = sqrtf(nx * nx + ny * ny + nz * nz);
    float invn = 1.f / (nn + EPS);
    float px = nx * invn, py = ny * invn, pz = nz * invn;

    float s0 = vnx[0] * px + vny[0] * py + vnz[0] * pz;
    float s1 = vnx[1] * px + vny[1] * py + vnz[1] * pz;
    float s2 = vnx[2] * px + vny[2] * py + vnz[2] * pz;
    float best = s0; int kb = 0;
    if (s1 > best) { best = s1; kb = 1; }
    if (s2 > best) { best = s2; kb = 2; }
    if (-s0 > best) { best = -s0; kb = 0; }
    if (-s1 > best) { best = -s1; kb = 1; }
    if (-s2 > best) { best = -s2; kb = 2; }
    float pnn = sqrtf(px * px + py * py + pz * pz);
    float cossim = best / (pnn * an[kb] + EPS);
    if (isnan(cossim)) cossim = 1.0f;
    float contrib = (best > MMAP_COS_THRESH) ? (1.f - cossim) : 0.f;

    sums[0] += smooth_c; sums[1] += cut; sums[2] += contrib;
  }
  block_reduce_add<3>(sums, acc, 2);
}

__global__ void finalize_kernel(const double* __restrict__ acc, float* __restrict__ out) {
  if (threadIdx.x == 0 && blockIdx.x == 0) {
    double a[5];
    #pragma unroll
    for (int v = 0; v < 5; v++) {
      double s = 0.0;
      for (int i = 0; i < NBIN; i++) s += acc[v * NBIN + i];
      a[v] = s;
    }
    double photo = a[0] / (a[1] + (double)EPS);
    double smooth = a[2] / (a[3] + (double)EPS);
    double norml = a[4] / (double)((size_t)BB * HW);
    out[0] = (float)(photo + 0.1 * smooth + (double)LAMBDA_NORM * norml);
  }
}

extern "C" void kernel_launch(void* const* d_in, const int* in_sizes, int n_in,
                              void* d_out, int out_size, void* d_ws, size_t ws_size,
                              hipStream_t stream) {
  (void)in_sizes; (void)n_in; (void)out_size; (void)ws_size;
  const float* left_rgb = (const float*)d_in[0];
  const float* left_depth = (const float*)d_in[1];
  const float* up_depth = (const float*)d_in[2];
  const float* up_rgb = (const float*)d_in[3];
  const float* vps = (const float*)d_in[4];

  double* acc = (double*)d_ws;               // 5 vars x NBIN doubles = 2560 B
  float* warp = (float*)((char*)d_ws + 4096);

  hipMemsetAsync(d_ws, 0, 5 * NBIN * sizeof(double), stream);
  splat_kernel<<<BB * (WDIM / SW), 256, 0, stream>>>(left_rgb, left_depth, warp);
  photo_kernel<<<BB * (HDIM / 32) * (WDIM / 32), 256, 0, stream>>>(warp, up_rgb, up_depth, acc);
  smoothnorm_kernel<<<BB * 128, 256, 0, stream>>>(left_rgb, left_depth, up_depth, vps, acc);
  finalize_kernel<<<1, 64, 0, stream>>>(acc, (float*)d_out);
}

// Round 7
// 330.570 us; speedup vs baseline: 1.3110x; 1.1521x over previous
//
#include <hip/hip_runtime.h>
#include <math.h>

#define HDIM 256
#define WDIM 512
#define BB 32
#define HW (HDIM*WDIM)
#define NBIN 64   // accumulator replicas per variable (atomic de-contention)
#define SW 8      // splat strip width (cols per block)
#define STR 260   // transposed LDS stride (floats): 1040B, 16B-aligned, bank-spread

constexpr float PI_F = 3.14159265358979323846f;
constexpr float DEPTH_THRESH = 10.0f;
constexpr float BASELINE = 0.26f;
constexpr float ALPHA = 0.85f;
constexpr float LAMBDA_NORM = 0.05f;
constexpr float MMAP_COS_THRESH = 0.9f;
constexpr float EPS = 1e-6f;

__device__ __forceinline__ float attn_of_h(int h) {
  float theta = ((h + 0.5f) * (1.0f / HDIM) - 0.5f) * PI_F;
  float a = 1.0f - fabsf(theta) / (0.5f * PI_F);
  return fminf(fmaxf(a, 0.0f), 1.0f);
}

// acc layout: acc[var * NBIN + bin], vars 0..4
template <int N>
__device__ __forceinline__ void block_reduce_add(float (&v)[N], double* acc, int base) {
  #pragma unroll
  for (int off = 32; off; off >>= 1) {
    #pragma unroll
    for (int j = 0; j < N; j++) v[j] += __shfl_down(v[j], off);
  }
  __shared__ float sb[N * 4];
  int wid = threadIdx.x >> 6, lane = threadIdx.x & 63;
  if (lane == 0) {
    #pragma unroll
    for (int j = 0; j < N; j++) sb[j * 4 + wid] = v[j];
  }
  __syncthreads();
  if (threadIdx.x == 0) {
    int bin = blockIdx.x & (NBIN - 1);
    #pragma unroll
    for (int j = 0; j < N; j++) {
      float s = sb[j * 4 + 0] + sb[j * 4 + 1] + sb[j * 4 + 2] + sb[j * 4 + 3];
      unsafeAtomicAdd(&acc[(base + j) * NBIN + bin], (double)s);
    }
  }
}

// ---------------- Splat: vertical 2-tap forward warp, GATHER + tent filter ----------
// No atomics, no branches in the scan. shift = atan(B*cos(th)/(d - B*sin(th)))*H/pi
// lies in (0, 44.6], so output h receives only from sources s in [h, h+45].
// Tent identity: tap weight at row h from source with coord cv is max(0, 1-|cv-h|)
// (== (1-dv) for floor(cv)==h, == dv for floor(cv)==h-1; exact in fp32 here).
// Each thread owns 8 consecutive rows of one column: one 53-source window serves
// all 8 outputs; cv+rgb scanned as b128 streams; branchless fma accumulation.
__global__ __launch_bounds__(256, 4) void splat_kernel(
    const float* __restrict__ rgb, const float* __restrict__ depth,
    float* __restrict__ outw) {
  __shared__ float cv_t[SW][STR], r_t[SW][STR], g_t[SW][STR], b_t[SW][STR];
  __shared__ float sTT[HDIM], cTT[HDIM];
  int blk = blockIdx.x;
  int b = blk >> 6;            // 64 strips of 8 cols per image
  int w0 = (blk & 63) << 3;
  int t = threadIdx.x;
  {
    float th = ((t + 0.5f) * (1.0f / HDIM) - 0.5f) * PI_F;
    sTT[t] = sinf(th); cTT[t] = cosf(th);
  }
  __syncthreads();

  const float* dep = depth + (size_t)b * HW;
  const float* rg  = rgb + (size_t)b * 3 * HW;
  const float scale = (float)HDIM / PI_F;

  // ---- stage: cv + rgb into transposed LDS ----
  {
    int wq = t & 1;            // which float4 (cols 0-3 / 4-7)
    int rr0 = t >> 1;          // rows 0..127, then +128
    #pragma unroll
    for (int half = 0; half < 2; ++half) {
      int row = rr0 + (half << 7);
      int gg = row * WDIM + w0 + (wq << 2);
      float4 d4 = *(const float4*)(dep + gg);
      float4 r4 = *(const float4*)(rg + gg);
      float4 g4 = *(const float4*)(rg + HW + gg);
      float4 b4 = *(const float4*)(rg + 2 * HW + gg);
      float st = sTT[row], ct = cTT[row];
      float bct = BASELINE * ct, bst = BASELINE * st;
      float dd[4] = {d4.x, d4.y, d4.z, d4.w};
      float rr[4] = {r4.x, r4.y, r4.z, r4.w};
      float gg2[4] = {g4.x, g4.y, g4.z, g4.w};
      float bb2[4] = {b4.x, b4.y, b4.z, b4.w};
      #pragma unroll
      for (int j = 0; j < 4; j++) {
        float d = dd[j];
        float cv = (float)row - atanf(bct / (d - bst)) * scale;
        if (!(d < DEPTH_THRESH)) cv = 1e9f;   // sentinel: tent weight always 0
        int c = (wq << 2) + j;
        cv_t[c][row] = cv;
        r_t[c][row] = rr[j];
        g_t[c][row] = gg2[j];
        b_t[c][row] = bb2[j];
      }
    }
  }
  __syncthreads();

  // ---- gather: thread owns rows [r0, r0+8) of column col ----
  int col = t & 7;
  int rgrp = t >> 3;           // 0..31
  int r0 = rgrp << 3;
  float h0f = (float)r0;
  const float* cvrow = &cv_t[col][0];
  const float* rrow  = &r_t[col][0];
  const float* grow  = &g_t[col][0];
  const float* brow  = &b_t[col][0];
  float accw[8], ar[8], ag[8], ab[8];
  #pragma unroll
  for (int o = 0; o < 8; ++o) { accw[o] = 0.f; ar[o] = 0.f; ag[o] = 0.f; ab[o] = 0.f; }
  int gend = min(((r0 + 52) >> 2), 63);
  for (int g = rgrp << 1; g <= gend; ++g) {
    float4 c4 = *(const float4*)(cvrow + (g << 2));
    float4 r4 = *(const float4*)(rrow + (g << 2));
    float4 g4 = *(const float4*)(grow + (g << 2));
    float4 b4 = *(const float4*)(brow + (g << 2));
    float cs[4] = {c4.x, c4.y, c4.z, c4.w};
    float rs[4] = {r4.x, r4.y, r4.z, r4.w};
    float gs[4] = {g4.x, g4.y, g4.z, g4.w};
    float bs[4] = {b4.x, b4.y, b4.z, b4.w};
    #pragma unroll
    for (int j = 0; j < 4; ++j) {
      float a = cs[j] - h0f;
      #pragma unroll
      for (int o = 0; o < 8; ++o) {
        float w = fmaxf(0.f, 1.f - fabsf(a - (float)o));
        accw[o] += w;
        ar[o] = fmaf(w, rs[j], ar[o]);
        ag[o] = fmaf(w, gs[j], ag[o]);
        ab[o] = fmaf(w, bs[j], ab[o]);
      }
    }
  }
  size_t obase = (size_t)b * 3 * HW + w0 + col;
  #pragma unroll
  for (int o = 0; o < 8; ++o) {
    float inv = 1.f / fmaxf(accw[o], EPS);
    size_t oo = obase + (size_t)(r0 + o) * WDIM;
    outw[oo] = ar[o] * inv;
    outw[oo + HW] = ag[o] * inv;
    outw[oo + 2 * HW] = ab[o] * inv;
  }
}

// ---------------- Photo loss: separable 7x7 Gaussian SSIM + L1, tiled ----------
__global__ __launch_bounds__(256) void photo_kernel(
    const float* __restrict__ xw, const float* __restrict__ yr,
    const float* __restrict__ up_depth, double* __restrict__ acc) {
  __shared__ float xs[38 * 40];
  __shared__ float ys[38 * 40];
  __shared__ float rxs[1216], rys[1216], rxxs[1216], ryys[1216], rxys[1216];

  int bt = blockIdx.x;
  int b = bt >> 7;             // 128 tiles (8x16) per image
  int rem = bt & 127;
  int h0 = (rem >> 4) << 5;
  int w0 = (rem & 15) << 5;
  int t = threadIdx.x;

  float G[7];
  {
    float s = 0.f;
    #pragma unroll
    for (int i = 0; i < 7; i++) { float a = (float)(i - 3); G[i] = expf(-a * a / 4.5f); s += G[i]; }
    #pragma unroll
    for (int i = 0; i < 7; i++) G[i] /= s;
  }

  float dssim_a[4] = {0.f, 0.f, 0.f, 0.f};
  float l1_a[4] = {0.f, 0.f, 0.f, 0.f};
  const float C1 = 1e-4f, C2 = 9e-4f;

  for (int c = 0; c < 3; ++c) {
    const float* xp = xw + ((size_t)(b * 3 + c)) * HW;
    const float* yp = yr + ((size_t)(b * 3 + c)) * HW;
    __syncthreads();
    for (int i = t; i < 38 * 38; i += 256) {
      int r = i / 38, cc = i % 38;
      int gh = h0 - 3 + r, gw = w0 - 3 + cc;
      bool in = (gh >= 0) && (gh < HDIM) && (gw >= 0) && (gw < WDIM);
      float xv = in ? xp[gh * WDIM + gw] : 0.f;
      float yv = in ? yp[gh * WDIM + gw] : 0.f;
      xs[r * 40 + cc] = xv; ys[r * 40 + cc] = yv;
    }
    __syncthreads();
    for (int i = t; i < 1216; i += 256) {
      int r = i >> 5, cc = i & 31;
      const float* xrow = xs + r * 40 + cc;
      const float* yrow = ys + r * 40 + cc;
      float sx = 0.f, sy = 0.f, sxx = 0.f, syy = 0.f, sxy = 0.f;
      #pragma unroll
      for (int k = 0; k < 7; k++) {
        float gk = G[k]; float xv = xrow[k], yv = yrow[k];
        sx += gk * xv; sy += gk * yv;
        sxx += gk * xv * xv; syy += gk * yv * yv; sxy += gk * xv * yv;
      }
      rxs[i] = sx; rys[i] = sy; rxxs[i] = sxx; ryys[i] = syy; rxys[i] = sxy;
    }
    __syncthreads();
    #pragma unroll
    for (int q = 0; q < 4; q++) {
      int o = t + (q << 8);
      int oh = o >> 5, ow = o & 31;
      float mx = 0.f, my = 0.f, cxx = 0.f, cyy = 0.f, cxy = 0.f;
      #pragma unroll
      for (int k = 0; k < 7; k++) {
        float gk = G[k]; int ro = (oh + k) * 32 + ow;
        mx += gk * rxs[ro]; my += gk * rys[ro];
        cxx += gk * rxxs[ro]; cyy += gk * ryys[ro]; cxy += gk * rxys[ro];
      }
      float sxx = cxx - mx * mx, syy = cyy - my * my, sxy = cxy - mx * my;
      float ssim = ((2.f * mx * my + C1) * (2.f * sxy + C2)) /
                   ((mx * mx + my * my + C1) * (sxx + syy + C2));
      dssim_a[q] += (1.f - ssim) * 0.5f;
      l1_a[q] += fabsf(xs[(oh + 3) * 40 + ow + 3] - ys[(oh + 3) * 40 + ow + 3]);
    }
  }

  float sums[2] = {0.f, 0.f};
  #pragma unroll
  for (int q = 0; q < 4; q++) {
    int o = t + (q << 8);
    int oh = o >> 5, ow = o & 31;
    int h = h0 + oh, w = w0 + ow;
    float pl = ALPHA * (dssim_a[q] * (1.f / 3.f)) + (1.f - ALPHA) * (l1_a[q] * (1.f / 3.f));
    float cut = (up_depth[(size_t)b * HW + h * WDIM + w] < DEPTH_THRESH) ? 1.f : 0.f;
    float wm = cut * attn_of_h(h);
    sums[0] += pl * wm; sums[1] += wm;
  }
  block_reduce_add<2>(sums, acc, 0);
}

// ---------------- Smooth + normal losses (grid-stride: 4 px/thread) ----------
__global__ __launch_bounds__(256) void smoothnorm_kernel(
    const float* __restrict__ rgb, const float* __restrict__ depth,
    const float* __restrict__ up_depth, const float* __restrict__ vps,
    double* __restrict__ acc) {
  __shared__ float sT[HDIM], cT[HDIM], sP[WDIM], cP[WDIM];
  int t = threadIdx.x;
  if (t < HDIM) {
    float th = ((t + 0.5f) * (1.0f / HDIM) - 0.5f) * PI_F;
    sT[t] = sinf(th); cT[t] = cosf(th);
  }
  for (int i = t; i < WDIM; i += 256) {
    float ph = ((i + 0.5f) * (1.0f / WDIM) - 0.5f) * 2.0f * PI_F;
    sP[i] = sinf(ph); cP[i] = cosf(ph);
  }
  __syncthreads();

  int b = blockIdx.x >> 7;                     // 128 blocks per image
  int seg = (blockIdx.x & 127) << 10;          // 1024 px per block
  const float* dep = depth + (size_t)b * HW;
  const float* rg  = rgb + (size_t)b * 3 * HW;

  const float* vp = vps + b * 9;
  float vnx[3], vny[3], vnz[3], an[3];
  #pragma unroll
  for (int k = 0; k < 3; k++) {
    float vx = vp[3 * k], vy = vp[3 * k + 1], vz = vp[3 * k + 2];
    float vn = sqrtf(vx * vx + vy * vy + vz * vz);
    float iv = 1.f / (vn + EPS);
    vnx[k] = vx * iv; vny[k] = vy * iv; vnz[k] = vz * iv;
    an[k] = sqrtf(vnx[k] * vnx[k] + vny[k] * vny[k] + vnz[k] * vnz[k]);
  }

  float sums[3] = {0.f, 0.f, 0.f};

  #pragma unroll
  for (int p = 0; p < 4; ++p) {
    int hw = seg + (p << 8) + t;
    int h = hw >> 9, w = hw & (WDIM - 1);
    float d00 = dep[hw];

    float su = 0.f, gu = 0.f;
    if (w < WDIM - 1) {
      float d01 = dep[hw + 1];
      float ax = d01 * cT[h] * cP[w + 1] - d00 * cT[h] * cP[w];
      float ay = (d01 - d00) * sT[h];
      float az = d01 * cT[h] * sP[w + 1] - d00 * cT[h] * sP[w];
      su = fabsf(ax) + fabsf(ay) + fabsf(az);
      gu = fabsf(rg[hw + 1] - rg[hw]) + fabsf(rg[HW + hw + 1] - rg[HW + hw]) +
           fabsf(rg[2 * HW + hw + 1] - rg[2 * HW + hw]);
    }
    float sv = 0.f, gv = 0.f;
    if (h < HDIM - 1) {
      float d10 = dep[hw + WDIM];
      float ax = d10 * cT[h + 1] * cP[w] - d00 * cT[h] * cP[w];
      float ay = d10 * sT[h + 1] - d00 * sT[h];
      float az = d10 * cT[h + 1] * sP[w] - d00 * cT[h] * sP[w];
      sv = fabsf(ax) + fabsf(ay) + fabsf(az);
      gv = fabsf(rg[hw + WDIM] - rg[hw]) + fabsf(rg[HW + hw + WDIM] - rg[HW + hw]) +
           fabsf(rg[2 * HW + hw + WDIM] - rg[2 * HW + hw]);
    }
    float cut = (up_depth[(size_t)b * HW + hw] < DEPTH_THRESH) ? 1.f : 0.f;
    float wsm = (1.f - attn_of_h(h)) * cut;
    float smooth_c = (su * expf(-gu) + sv * expf(-gv)) * wsm;

    // normals (roll +/-3 with wrap on both axes)
    int wp = (w + 3) & (WDIM - 1), wmi = (w - 3) & (WDIM - 1);
    int hp = (h + 3) & (HDIM - 1), hm = (h - 3) & (HDIM - 1);
    float dwp = dep[h * WDIM + wp], dwm = dep[h * WDIM + wmi];
    float dhp = dep[hp * WDIM + w], dhm = dep[hm * WDIM + w];

    float pux = dwp * cT[h] * cP[wp] - dwm * cT[h] * cP[wmi];
    float puy = (dwp - dwm) * sT[h];
    float puz = dwp * cT[h] * sP[wp] - dwm * cT[h] * sP[wmi];
    float pvx = dhp * cT[hp] * cP[w] - dhm * cT[hm] * cP[w];
    float pvy = dhp * sT[hp] - dhm * sT[hm];
    float pvz = dhp * cT[hp] * sP[w] - dhm * cT[hm] * sP[w];
    // n = cross(dpv, dpu)
    float nx = pvy * puz - pvz * puy;
    float ny = pvz * pux - pvx * puz;
    float nz = pvx * puy - pvy * pux;
    float nn = sqrtf(nx * nx + ny * ny + nz * nz);
    float invn = 1.f / (nn + EPS);
    float px = nx * invn, py = ny * invn, pz = nz * invn;

    float s0 = vnx[0] * px + vny[0] * py + vnz[0] * pz;
    float s1 = vnx[1] * px + vny[1] * py + vnz[1] * pz;
    float s2 = vnx[2] * px + vny[2] * py + vnz[2] * pz;
    float best = s0; int kb = 0;
    if (s1 > best) { best = s1; kb = 1; }
    if (s2 > best) { best = s2; kb = 2; }
    if (-s0 > best) { best = -s0; kb = 0; }
    if (-s1 > best) { best = -s1; kb = 1; }
    if (-s2 > best) { best = -s2; kb = 2; }
    float pnn = sqrtf(px * px + py * py + pz * pz);
    float cossim = best / (pnn * an[kb] + EPS);
    if (isnan(cossim)) cossim = 1.0f;
    float contrib = (best > MMAP_COS_THRESH) ? (1.f - cossim) : 0.f;

    sums[0] += smooth_c; sums[1] += cut; sums[2] += contrib;
  }
  block_reduce_add<3>(sums, acc, 2);
}

__global__ void finalize_kernel(const double* __restrict__ acc, float* __restrict__ out) {
  if (threadIdx.x == 0 && blockIdx.x == 0) {
    double a[5];
    #pragma unroll
    for (int v = 0; v < 5; v++) {
      double s = 0.0;
      for (int i = 0; i < NBIN; i++) s += acc[v * NBIN + i];
      a[v] = s;
    }
    double photo = a[0] / (a[1] + (double)EPS);
    double smooth = a[2] / (a[3] + (double)EPS);
    double norml = a[4] / (double)((size_t)BB * HW);
    out[0] = (float)(photo + 0.1 * smooth + (double)LAMBDA_NORM * norml);
  }
}

extern "C" void kernel_launch(void* const* d_in, const int* in_sizes, int n_in,
                              void* d_out, int out_size, void* d_ws, size_t ws_size,
                              hipStream_t stream) {
  (void)in_sizes; (void)n_in; (void)out_size; (void)ws_size;
  const float* left_rgb = (const float*)d_in[0];
  const float* left_depth = (const float*)d_in[1];
  const float* up_depth = (const float*)d_in[2];
  const float* up_rgb = (const float*)d_in[3];
  const float* vps = (const float*)d_in[4];

  double* acc = (double*)d_ws;               // 5 vars x NBIN doubles = 2560 B
  float* warp = (float*)((char*)d_ws + 4096);

  hipMemsetAsync(d_ws, 0, 5 * NBIN * sizeof(double), stream);
  splat_kernel<<<BB * (WDIM / SW), 256, 0, stream>>>(left_rgb, left_depth, warp);
  photo_kernel<<<BB * (HDIM / 32) * (WDIM / 32), 256, 0, stream>>>(warp, up_rgb, up_depth, acc);
  smoothnorm_kernel<<<BB * 128, 256, 0, stream>>>(left_rgb, left_depth, up_depth, vps, acc);
  finalize_kernel<<<1, 64, 0, stream>>>(acc, (float*)d_out);
}

// Round 8
// 326.395 us; speedup vs baseline: 1.3278x; 1.0128x over previous
//
#include <hip/hip_runtime.h>
#include <math.h>

#define HDIM 256
#define WDIM 512
#define BB 32
#define HW (HDIM*WDIM)
#define NBIN 64   // accumulator replicas per variable (atomic de-contention)
#define SW 8      // splat strip width (cols per block)
#define STR 260   // transposed LDS stride (floats)

constexpr float PI_F = 3.14159265358979323846f;
constexpr float DEPTH_THRESH = 10.0f;
constexpr float BASELINE = 0.26f;
constexpr float ALPHA = 0.85f;
constexpr float LAMBDA_NORM = 0.05f;
constexpr float MMAP_COS_THRESH = 0.9f;
constexpr float EPS = 1e-6f;

__device__ __forceinline__ float attn_of_h(int h) {
  float theta = ((h + 0.5f) * (1.0f / HDIM) - 0.5f) * PI_F;
  float a = 1.0f - fabsf(theta) / (0.5f * PI_F);
  return fminf(fmaxf(a, 0.0f), 1.0f);
}

__device__ __forceinline__ float4 f4fma(float s, float4 a, float4 acc) {
  return make_float4(fmaf(s, a.x, acc.x), fmaf(s, a.y, acc.y),
                     fmaf(s, a.z, acc.z), fmaf(s, a.w, acc.w));
}

// acc layout: acc[var * NBIN + bin], vars 0..4
template <int N>
__device__ __forceinline__ void block_reduce_add(float (&v)[N], double* acc, int base) {
  #pragma unroll
  for (int off = 32; off; off >>= 1) {
    #pragma unroll
    for (int j = 0; j < N; j++) v[j] += __shfl_down(v[j], off);
  }
  __shared__ float sb[N * 4];
  int wid = threadIdx.x >> 6, lane = threadIdx.x & 63;
  if (lane == 0) {
    #pragma unroll
    for (int j = 0; j < N; j++) sb[j * 4 + wid] = v[j];
  }
  __syncthreads();
  if (threadIdx.x == 0) {
    int bin = blockIdx.x & (NBIN - 1);
    #pragma unroll
    for (int j = 0; j < N; j++) {
      float s = sb[j * 4 + 0] + sb[j * 4 + 1] + sb[j * 4 + 2] + sb[j * 4 + 3];
      unsafeAtomicAdd(&acc[(base + j) * NBIN + bin], (double)s);
    }
  }
}

// ---------------- Splat: vertical 2-tap forward warp, GATHER + tent filter ----------
__global__ __launch_bounds__(256, 4) void splat_kernel(
    const float* __restrict__ rgb, const float* __restrict__ depth,
    float* __restrict__ outw) {
  __shared__ float cv_t[SW][STR], r_t[SW][STR], g_t[SW][STR], b_t[SW][STR];
  __shared__ float sTT[HDIM], cTT[HDIM];
  int blk = blockIdx.x;
  int b = blk >> 6;            // 64 strips of 8 cols per image
  int w0 = (blk & 63) << 3;
  int t = threadIdx.x;
  {
    float th = ((t + 0.5f) * (1.0f / HDIM) - 0.5f) * PI_F;
    sTT[t] = sinf(th); cTT[t] = cosf(th);
  }
  __syncthreads();

  const float* dep = depth + (size_t)b * HW;
  const float* rg  = rgb + (size_t)b * 3 * HW;
  const float scale = (float)HDIM / PI_F;

  // ---- stage: cv + rgb into transposed LDS ----
  {
    int wq = t & 1;
    int rr0 = t >> 1;
    #pragma unroll
    for (int half = 0; half < 2; ++half) {
      int row = rr0 + (half << 7);
      int gg = row * WDIM + w0 + (wq << 2);
      float4 d4 = *(const float4*)(dep + gg);
      float4 r4 = *(const float4*)(rg + gg);
      float4 g4 = *(const float4*)(rg + HW + gg);
      float4 b4 = *(const float4*)(rg + 2 * HW + gg);
      float st = sTT[row], ct = cTT[row];
      float bct = BASELINE * ct, bst = BASELINE * st;
      float dd[4] = {d4.x, d4.y, d4.z, d4.w};
      float rr[4] = {r4.x, r4.y, r4.z, r4.w};
      float gg2[4] = {g4.x, g4.y, g4.z, g4.w};
      float bb2[4] = {b4.x, b4.y, b4.z, b4.w};
      #pragma unroll
      for (int j = 0; j < 4; j++) {
        float d = dd[j];
        float cv = (float)row - atanf(bct / (d - bst)) * scale;
        if (!(d < DEPTH_THRESH)) cv = 1e9f;
        int c = (wq << 2) + j;
        cv_t[c][row] = cv;
        r_t[c][row] = rr[j];
        g_t[c][row] = gg2[j];
        b_t[c][row] = bb2[j];
      }
    }
  }
  __syncthreads();

  // ---- gather: thread owns rows [r0, r0+8) of column col ----
  int col = t & 7;
  int rgrp = t >> 3;
  int r0 = rgrp << 3;
  float h0f = (float)r0;
  const float* cvrow = &cv_t[col][0];
  const float* rrow  = &r_t[col][0];
  const float* grow  = &g_t[col][0];
  const float* brow  = &b_t[col][0];
  float accw[8], ar[8], ag[8], ab[8];
  #pragma unroll
  for (int o = 0; o < 8; ++o) { accw[o] = 0.f; ar[o] = 0.f; ag[o] = 0.f; ab[o] = 0.f; }
  int gend = min(((r0 + 52) >> 2), 63);
  for (int g = rgrp << 1; g <= gend; ++g) {
    float4 c4 = *(const float4*)(cvrow + (g << 2));
    float4 r4 = *(const float4*)(rrow + (g << 2));
    float4 g4 = *(const float4*)(grow + (g << 2));
    float4 b4 = *(const float4*)(brow + (g << 2));
    float cs[4] = {c4.x, c4.y, c4.z, c4.w};
    float rs[4] = {r4.x, r4.y, r4.z, r4.w};
    float gs[4] = {g4.x, g4.y, g4.z, g4.w};
    float bs[4] = {b4.x, b4.y, b4.z, b4.w};
    #pragma unroll
    for (int j = 0; j < 4; ++j) {
      float a = cs[j] - h0f;
      #pragma unroll
      for (int o = 0; o < 8; ++o) {
        float w = fmaxf(0.f, 1.f - fabsf(a - (float)o));
        accw[o] += w;
        ar[o] = fmaf(w, rs[j], ar[o]);
        ag[o] = fmaf(w, gs[j], ag[o]);
        ab[o] = fmaf(w, bs[j], ab[o]);
      }
    }
  }
  size_t obase = (size_t)b * 3 * HW + w0 + col;
  #pragma unroll
  for (int o = 0; o < 8; ++o) {
    float inv = 1.f / fmaxf(accw[o], EPS);
    size_t oo = obase + (size_t)(r0 + o) * WDIM;
    outw[oo] = ar[o] * inv;
    outw[oo + HW] = ag[o] * inv;
    outw[oo + 2 * HW] = ab[o] * inv;
  }
}

// ---------------- Photo loss: separable 7x7 SSIM + L1, b128-vectorized LDS ----------
__global__ __launch_bounds__(256) void photo_kernel(
    const float* __restrict__ xw, const float* __restrict__ yr,
    const float* __restrict__ up_depth, double* __restrict__ acc) {
  __shared__ float xs[38 * 40];
  __shared__ float ys[38 * 40];
  __shared__ float rxs[1216], rys[1216], rxxs[1216], ryys[1216], rxys[1216];

  int bt = blockIdx.x;
  int b = bt >> 7;             // 128 tiles (8x16) per image
  int rem = bt & 127;
  int h0 = (rem >> 4) << 5;
  int w0 = (rem & 15) << 5;
  int t = threadIdx.x;

  float G[7];
  {
    float s = 0.f;
    #pragma unroll
    for (int i = 0; i < 7; i++) { float a = (float)(i - 3); G[i] = expf(-a * a / 4.5f); s += G[i]; }
    #pragma unroll
    for (int i = 0; i < 7; i++) G[i] /= s;
  }

  int oh = t >> 3;             // this thread's output row (0..31)
  int cc = (t & 7) << 2;       // this thread's 4 output cols

  float dssim_a[4] = {0.f, 0.f, 0.f, 0.f};
  float l1_a[4] = {0.f, 0.f, 0.f, 0.f};
  const float C1 = 1e-4f, C2 = 9e-4f;

  for (int c = 0; c < 3; ++c) {
    const float* xp = xw + ((size_t)(b * 3 + c)) * HW;
    const float* yp = yr + ((size_t)(b * 3 + c)) * HW;
    __syncthreads();
    // ---- stage 38x38 tile (+0 pad) ----
    for (int i = t; i < 38 * 38; i += 256) {
      int r = i / 38, k = i % 38;
      int gh = h0 - 3 + r, gw = w0 - 3 + k;
      bool in = (gh >= 0) && (gh < HDIM) && (gw >= 0) && (gw < WDIM);
      float xv = in ? xp[gh * WDIM + gw] : 0.f;
      float yv = in ? yp[gh * WDIM + gw] : 0.f;
      xs[r * 40 + k] = xv; ys[r * 40 + k] = yv;
    }
    __syncthreads();
    // ---- row (horizontal) pass: 38 rows x 8 col-groups, b128 in/out ----
    for (int i = t; i < 304; i += 256) {
      int r = i >> 3, c4 = (i & 7) << 2;
      const float* xrow = xs + r * 40 + c4;
      const float* yrow = ys + r * 40 + c4;
      float4 a0 = *(const float4*)(xrow);
      float4 a1 = *(const float4*)(xrow + 4);
      float4 a2 = *(const float4*)(xrow + 8);
      float4 b0 = *(const float4*)(yrow);
      float4 b1 = *(const float4*)(yrow + 4);
      float4 b2 = *(const float4*)(yrow + 8);
      float xv[12] = {a0.x,a0.y,a0.z,a0.w,a1.x,a1.y,a1.z,a1.w,a2.x,a2.y,a2.z,a2.w};
      float yv[12] = {b0.x,b0.y,b0.z,b0.w,b1.x,b1.y,b1.z,b1.w,b2.x,b2.y,b2.z,b2.w};
      float px[10], py[10], pxy[10];
      #pragma unroll
      for (int j = 0; j < 10; j++) {
        px[j] = xv[j] * xv[j]; py[j] = yv[j] * yv[j]; pxy[j] = xv[j] * yv[j];
      }
      float sx[4], sy[4], sxx[4], syy[4], sxy[4];
      #pragma unroll
      for (int o = 0; o < 4; o++) {
        sx[o]  = G[3]*xv[o+3]  + G[0]*(xv[o]+xv[o+6])   + G[1]*(xv[o+1]+xv[o+5])   + G[2]*(xv[o+2]+xv[o+4]);
        sy[o]  = G[3]*yv[o+3]  + G[0]*(yv[o]+yv[o+6])   + G[1]*(yv[o+1]+yv[o+5])   + G[2]*(yv[o+2]+yv[o+4]);
        sxx[o] = G[3]*px[o+3]  + G[0]*(px[o]+px[o+6])   + G[1]*(px[o+1]+px[o+5])   + G[2]*(px[o+2]+px[o+4]);
        syy[o] = G[3]*py[o+3]  + G[0]*(py[o]+py[o+6])   + G[1]*(py[o+1]+py[o+5])   + G[2]*(py[o+2]+py[o+4]);
        sxy[o] = G[3]*pxy[o+3] + G[0]*(pxy[o]+pxy[o+6]) + G[1]*(pxy[o+1]+pxy[o+5]) + G[2]*(pxy[o+2]+pxy[o+4]);
      }
      int ro = r * 32 + c4;
      *(float4*)(rxs  + ro) = make_float4(sx[0],  sx[1],  sx[2],  sx[3]);
      *(float4*)(rys  + ro) = make_float4(sy[0],  sy[1],  sy[2],  sy[3]);
      *(float4*)(rxxs + ro) = make_float4(sxx[0], sxx[1], sxx[2], sxx[3]);
      *(float4*)(ryys + ro) = make_float4(syy[0], syy[1], syy[2], syy[3]);
      *(float4*)(rxys + ro) = make_float4(sxy[0], sxy[1], sxy[2], sxy[3]);
    }
    __syncthreads();
    // ---- col (vertical) pass: thread owns (oh, cc..cc+3) ----
    float4 mx = make_float4(0,0,0,0), my = mx, cxx = mx, cyy = mx, cxy = mx;
    #pragma unroll
    for (int k = 0; k < 7; k++) {
      int ro = (oh + k) * 32 + cc;
      mx  = f4fma(G[k], *(const float4*)(rxs  + ro), mx);
      my  = f4fma(G[k], *(const float4*)(rys  + ro), my);
      cxx = f4fma(G[k], *(const float4*)(rxxs + ro), cxx);
      cyy = f4fma(G[k], *(const float4*)(ryys + ro), cyy);
      cxy = f4fma(G[k], *(const float4*)(rxys + ro), cxy);
    }
    float mxa[4] = {mx.x, mx.y, mx.z, mx.w};
    float mya[4] = {my.x, my.y, my.z, my.w};
    float xxa[4] = {cxx.x, cxx.y, cxx.z, cxx.w};
    float yya[4] = {cyy.x, cyy.y, cyy.z, cyy.w};
    float xya[4] = {cxy.x, cxy.y, cxy.z, cxy.w};
    #pragma unroll
    for (int j = 0; j < 4; j++) {
      float sxx = xxa[j] - mxa[j] * mxa[j];
      float syy = yya[j] - mya[j] * mya[j];
      float sxy = xya[j] - mxa[j] * mya[j];
      float ssim = ((2.f * mxa[j] * mya[j] + C1) * (2.f * sxy + C2)) /
                   ((mxa[j] * mxa[j] + mya[j] * mya[j] + C1) * (sxx + syy + C2));
      dssim_a[j] += (1.f - ssim) * 0.5f;
      int ci = (oh + 3) * 40 + cc + 3 + j;
      l1_a[j] += fabsf(xs[ci] - ys[ci]);
    }
  }

  float sums[2] = {0.f, 0.f};
  {
    int h = h0 + oh;
    float at = attn_of_h(h);
    float4 ud = *(const float4*)(up_depth + (size_t)b * HW + h * WDIM + w0 + cc);
    float uda[4] = {ud.x, ud.y, ud.z, ud.w};
    #pragma unroll
    for (int j = 0; j < 4; j++) {
      float pl = ALPHA * (dssim_a[j] * (1.f / 3.f)) + (1.f - ALPHA) * (l1_a[j] * (1.f / 3.f));
      float cut = (uda[j] < DEPTH_THRESH) ? 1.f : 0.f;
      float wm = cut * at;
      sums[0] += pl * wm; sums[1] += wm;
    }
  }
  block_reduce_add<2>(sums, acc, 0);
}

// ---------------- Smooth + normal losses (grid-stride: 4 px/thread) ----------
__global__ __launch_bounds__(256) void smoothnorm_kernel(
    const float* __restrict__ rgb, const float* __restrict__ depth,
    const float* __restrict__ up_depth, const float* __restrict__ vps,
    double* __restrict__ acc) {
  __shared__ float sT[HDIM], cT[HDIM], sP[WDIM], cP[WDIM];
  int t = threadIdx.x;
  if (t < HDIM) {
    float th = ((t + 0.5f) * (1.0f / HDIM) - 0.5f) * PI_F;
    sT[t] = sinf(th); cT[t] = cosf(th);
  }
  for (int i = t; i < WDIM; i += 256) {
    float ph = ((i + 0.5f) * (1.0f / WDIM) - 0.5f) * 2.0f * PI_F;
    sP[i] = sinf(ph); cP[i] = cosf(ph);
  }
  __syncthreads();

  int b = blockIdx.x >> 7;
  int seg = (blockIdx.x & 127) << 10;
  const float* dep = depth + (size_t)b * HW;
  const float* rg  = rgb + (size_t)b * 3 * HW;

  const float* vp = vps + b * 9;
  float vnx[3], vny[3], vnz[3], an[3];
  #pragma unroll
  for (int k = 0; k < 3; k++) {
    float vx = vp[3 * k], vy = vp[3 * k + 1], vz = vp[3 * k + 2];
    float vn = sqrtf(vx * vx + vy * vy + vz * vz);
    float iv = 1.f / (vn + EPS);
    vnx[k] = vx * iv; vny[k] = vy * iv; vnz[k] = vz * iv;
    an[k] = sqrtf(vnx[k] * vnx[k] + vny[k] * vny[k] + vnz[k] * vnz[k]);
  }

  float sums[3] = {0.f, 0.f, 0.f};

  #pragma unroll
  for (int p = 0; p < 4; ++p) {
    int hw = seg + (p << 8) + t;
    int h = hw >> 9, w = hw & (WDIM - 1);
    float d00 = dep[hw];

    float su = 0.f, gu = 0.f;
    if (w < WDIM - 1) {
      float d01 = dep[hw + 1];
      float ax = d01 * cT[h] * cP[w + 1] - d00 * cT[h] * cP[w];
      float ay = (d01 - d00) * sT[h];
      float az = d01 * cT[h] * sP[w + 1] - d00 * cT[h] * sP[w];
      su = fabsf(ax) + fabsf(ay) + fabsf(az);
      gu = fabsf(rg[hw + 1] - rg[hw]) + fabsf(rg[HW + hw + 1] - rg[HW + hw]) +
           fabsf(rg[2 * HW + hw + 1] - rg[2 * HW + hw]);
    }
    float sv = 0.f, gv = 0.f;
    if (h < HDIM - 1) {
      float d10 = dep[hw + WDIM];
      float ax = d10 * cT[h + 1] * cP[w] - d00 * cT[h] * cP[w];
      float ay = d10 * sT[h + 1] - d00 * sT[h];
      float az = d10 * cT[h + 1] * sP[w] - d00 * cT[h] * sP[w];
      sv = fabsf(ax) + fabsf(ay) + fabsf(az);
      gv = fabsf(rg[hw + WDIM] - rg[hw]) + fabsf(rg[HW + hw + WDIM] - rg[HW + hw]) +
           fabsf(rg[2 * HW + hw + WDIM] - rg[2 * HW + hw]);
    }
    float cut = (up_depth[(size_t)b * HW + hw] < DEPTH_THRESH) ? 1.f : 0.f;
    float wsm = (1.f - attn_of_h(h)) * cut;
    float smooth_c = (su * expf(-gu) + sv * expf(-gv)) * wsm;

    int wp = (w + 3) & (WDIM - 1), wmi = (w - 3) & (WDIM - 1);
    int hp = (h + 3) & (HDIM - 1), hm = (h - 3) & (HDIM - 1);
    float dwp = dep[h * WDIM + wp], dwm = dep[h * WDIM + wmi];
    float dhp = dep[hp * WDIM + w], dhm = dep[hm * WDIM + w];

    float pux = dwp * cT[h] * cP[wp] - dwm * cT[h] * cP[wmi];
    float puy = (dwp - dwm) * sT[h];
    float puz = dwp * cT[h] * sP[wp] - dwm * cT[h] * sP[wmi];
    float pvx = dhp * cT[hp] * cP[w] - dhm * cT[hm] * cP[w];
    float pvy = dhp * sT[hp] - dhm * sT[hm];
    float pvz = dhp * cT[hp] * sP[w] - dhm * cT[hm] * sP[w];
    float nx = pvy * puz - pvz * puy;
    float ny = pvz * pux - pvx * puz;
    float nz = pvx * puy - pvy * pux;
    float nn = sqrtf(nx * nx + ny * ny + nz * nz);
    float invn = 1.f / (nn + EPS);
    float px = nx * invn, py = ny * invn, pz = nz * invn;

    float s0 = vnx[0] * px + vny[0] * py + vnz[0] * pz;
    float s1 = vnx[1] * px + vny[1] * py + vnz[1] * pz;
    float s2 = vnx[2] * px + vny[2] * py + vnz[2] * pz;
    float best = s0; int kb = 0;
    if (s1 > best) { best = s1; kb = 1; }
    if (s2 > best) { best = s2; kb = 2; }
    if (-s0 > best) { best = -s0; kb = 0; }
    if (-s1 > best) { best = -s1; kb = 1; }
    if (-s2 > best) { best = -s2; kb = 2; }
    float pnn = sqrtf(px * px + py * py + pz * pz);
    float cossim = best / (pnn * an[kb] + EPS);
    if (isnan(cossim)) cossim = 1.0f;
    float contrib = (best > MMAP_COS_THRESH) ? (1.f - cossim) : 0.f;

    sums[0] += smooth_c; sums[1] += cut; sums[2] += contrib;
  }
  block_reduce_add<3>(sums, acc, 2);
}

__global__ void finalize_kernel(const double* __restrict__ acc, float* __restrict__ out) {
  if (threadIdx.x == 0 && blockIdx.x == 0) {
    double a[5];
    #pragma unroll
    for (int v = 0; v < 5; v++) {
      double s = 0.0;
      for (int i = 0; i < NBIN; i++) s += acc[v * NBIN + i];
      a[v] = s;
    }
    double photo = a[0] / (a[1] + (double)EPS);
    double smooth = a[2] / (a[3] + (double)EPS);
    double norml = a[4] / (double)((size_t)BB * HW);
    out[0] = (float)(photo + 0.1 * smooth + (double)LAMBDA_NORM * norml);
  }
}

extern "C" void kernel_launch(void* const* d_in, const int* in_sizes, int n_in,
                              void* d_out, int out_size, void* d_ws, size_t ws_size,
                              hipStream_t stream) {
  (void)in_sizes; (void)n_in; (void)out_size; (void)ws_size;
  const float* left_rgb = (const float*)d_in[0];
  const float* left_depth = (const float*)d_in[1];
  const float* up_depth = (const float*)d_in[2];
  const float* up_rgb = (const float*)d_in[3];
  const float* vps = (const float*)d_in[4];

  double* acc = (double*)d_ws;               // 5 vars x NBIN doubles = 2560 B
  float* warp = (float*)((char*)d_ws + 4096);

  hipMemsetAsync(d_ws, 0, 5 * NBIN * sizeof(double), stream);
  splat_kernel<<<BB * (WDIM / SW), 256, 0, stream>>>(left_rgb, left_depth, warp);
  photo_kernel<<<BB * (HDIM / 32) * (WDIM / 32), 256, 0, stream>>>(warp, up_rgb, up_depth, acc);
  smoothnorm_kernel<<<BB * 128, 256, 0, stream>>>(left_rgb, left_depth, up_depth, vps, acc);
  finalize_kernel<<<1, 64, 0, stream>>>(acc, (float*)d_out);
}